// Round 8
// baseline (259.358 us; speedup 1.0000x reference)
//
#include <hip/hip_runtime.h>
#include <stdint.h>

#define NVOX 40000
#define CCH  128
#define K2   9
#define NH   5
#define TILES 313   // ceil(40000/128)

typedef __attribute__((ext_vector_type(8))) short bf16x8;
typedef __attribute__((ext_vector_type(4))) float f32x4;

__device__ __forceinline__ unsigned short f2b(float f) {
  union { float f; unsigned int u; } v; v.f = f;
  return (unsigned short)((v.u + 0x7fffu + ((v.u >> 16) & 1u)) >> 16);
}
__device__ __forceinline__ float b2f(unsigned short u) {
  union { unsigned int u; float f; } v; v.u = ((unsigned int)u) << 16;
  return v.f;
}
__device__ __forceinline__ void g2l16(const void* g, void* l) {
  __builtin_amdgcn_global_load_lds(
      (const __attribute__((address_space(1))) unsigned int*)g,
      (__attribute__((address_space(3))) unsigned int*)l, 16, 0, 0);
}
// XOR-swizzled LDS address (shorts) for logical (row, short-col), 128-wide
__device__ __forceinline__ int swz(int row, int col) {
  return row * 128 + ((((col >> 3) ^ (row & 15)) << 3) | (col & 7));
}

// ---- fused prep: feats fp32->bf16 | W1 cvt+transpose | sums zero ----
__global__ void prep(const float4* __restrict__ feats, ushort4* __restrict__ fb,
                     const float* __restrict__ w1, unsigned short* __restrict__ w1t,
                     float* __restrict__ sums) {
  __shared__ unsigned short t[128 * 34];
  int b = blockIdx.x;
  if (b < 5000) {
    int i = b * 256 + threadIdx.x;
    if (i < NVOX * CCH / 4) {
      float4 v = feats[i];
      ushort4 r;
      r.x = f2b(v.x); r.y = f2b(v.y); r.z = f2b(v.z); r.w = f2b(v.w);
      fb[i] = r;
    }
    return;
  }
  if (b == 5180) {  // zero BN partial sums (ws is poisoned each call)
    for (int i = threadIdx.x; i < 2 * NH * CCH; i += 256) sums[i] = 0.f;
    return;
  }
  int bb = b - 5000;           // 0..179
  int tile = bb >> 2;          // h*9+k, 0..44
  int q = bb & 3;              // c-quarter
  const float* src = w1 + (size_t)tile * 16384 + q * 32 * 128;
  for (int e = threadIdx.x; e < 4096; e += 256) {
    int c = e >> 7, d = e & 127;
    t[d * 34 + c] = f2b(src[e]);
  }
  __syncthreads();
  unsigned short* dst = w1t + (size_t)tile * 16384 + q * 32;
  for (int e = threadIdx.x; e < 4096; e += 256) {
    int d = e >> 5, c = e & 31;
    dst[d * 128 + c] = t[d * 34 + c];
  }
}

// stage one HALF B tile (128 rows x 64 cols = 16 KB) into LDS, swizzled:
// slot = gchunk ^ (row&7). 4 g2l16 per wave; each op covers 8 rows x 64 cols
// = 512 shorts (1 KB).
__device__ __forceinline__ void stageBhalf(unsigned short* dst, const unsigned short* wp,
                                           int half, int wave, int lane) {
  int lrow = lane >> 3;   // 0..7
  int lch  = lane & 7;    // chunk slot
#pragma unroll
  for (int i = 0; i < 4; ++i) {
    int rb = (wave * 4 + i) * 8;
    g2l16(wp + (rb + lrow) * 128 + half * 64 + ((lch ^ lrow) << 3),
          &dst[(wave * 4 + i) * 512]);
  }
}

// ---- gather-GEMM v7b: A fragments in registers (prefetched one tap ahead,
// per-wave private rows); B staged in 16 KB HALF-tiles, double-buffered
// (2x16 KB LDS) -> 4 blocks/CU, 16 waves/CU. 18 half-phases, stage(p+1) in
// flight across compute(p). ----
__global__ void __launch_bounds__(256, 4) conv_gemm(
    const unsigned short* __restrict__ fb,   // feats bf16 [N][128]
    const int* __restrict__ nbr,             // [N][9]
    const unsigned short* __restrict__ w1t,  // [H][9][d=128][c=128] bf16
    unsigned short* __restrict__ yb,         // [H][N][128] bf16
    float* __restrict__ sums)                // [2][H][128]
{
  __shared__ __align__(16) unsigned short Bsb[2][64 * 128];   // 2 x 16 KB
  __shared__ int idxs[128 * K2];                              // 4.6 KB

  const int bid = blockIdx.x;
  const int s = bid / 40;
  const int r = bid % 40;
  const int h = r >> 3;        // 0..4
  const int x = r & 7;         // xcd lane
  const int tile = s * 8 + x;
  if (tile >= TILES) return;
  const int n0 = tile * 128;

  const int tid = threadIdx.x;
  const int wave = tid >> 6;
  const int lane = tid & 63;
  const int m = lane & 15;     // position within 16
  const int quad = lane >> 4;  // 0..3

  const unsigned short* wh = w1t + ((size_t)h * K2 << 14);

  // phase (k=0, half=0) stage first (no dependencies)
  stageBhalf(Bsb[0], wh, 0, wave, lane);

  for (int i = tid; i < 128 * K2; i += 256) {
    int rr = i / K2;
    int gn = n0 + rr; if (gn > NVOX - 1) gn = NVOX - 1;
    idxs[i] = nbr[gn * K2 + (i - rr * K2)];
  }
  __syncthreads();   // idxs visible

  // A parity registers: [par][mi][kc], each bf16x8 (wave-private rows)
  bf16x8 A[2][2][4];
  {
    int i0 = idxs[(wave * 32 + m) * K2 + 0];
    int i1 = idxs[(wave * 32 + 16 + m) * K2 + 0];
    const unsigned short* p0 = fb + (size_t)i0 * CCH + quad * 8;
    const unsigned short* p1 = fb + (size_t)i1 * CCH + quad * 8;
#pragma unroll
    for (int kc = 0; kc < 4; ++kc) {
      A[0][0][kc] = *(const bf16x8*)(p0 + kc * 32);
      A[0][1][kc] = *(const bf16x8*)(p1 + kc * 32);
    }
  }
  asm volatile("s_waitcnt vmcnt(0)" ::: "memory");
  __syncthreads();   // B(0,h0) + A(0) ready

  f32x4 acc[2][8] = {};

#pragma unroll
  for (int k = 0; k < K2; ++k) {
    const int par = k & 1;

    // ---- half-phase 0: compute kc 0,1 from Bsb[0] ----
    stageBhalf(Bsb[1], wh + ((size_t)k << 14), 1, wave, lane);  // B(k,h1)
    if (k + 1 < K2) {  // A(k+1) register prefetch (private, no barrier)
      int i0 = idxs[(wave * 32 + m) * K2 + k + 1];
      int i1 = idxs[(wave * 32 + 16 + m) * K2 + k + 1];
      const unsigned short* p0 = fb + (size_t)i0 * CCH + quad * 8;
      const unsigned short* p1 = fb + (size_t)i1 * CCH + quad * 8;
#pragma unroll
      for (int kc = 0; kc < 4; ++kc) {
        A[par ^ 1][0][kc] = *(const bf16x8*)(p0 + kc * 32);
        A[par ^ 1][1][kc] = *(const bf16x8*)(p1 + kc * 32);
      }
    }
#pragma unroll
    for (int kc = 0; kc < 2; ++kc) {
      bf16x8 bfr[8];
#pragma unroll
      for (int ni = 0; ni < 8; ++ni)
        bfr[ni] = *(const bf16x8*)&Bsb[0][(ni * 16 + m) * 64 + ((((kc & 1) * 4 + quad) ^ (m & 7)) << 3)];
#pragma unroll
      for (int ni = 0; ni < 8; ++ni) {
        acc[0][ni] = __builtin_amdgcn_mfma_f32_16x16x32_bf16(A[par][0][kc], bfr[ni], acc[0][ni], 0, 0, 0);
        acc[1][ni] = __builtin_amdgcn_mfma_f32_16x16x32_bf16(A[par][1][kc], bfr[ni], acc[1][ni], 0, 0, 0);
      }
    }
    asm volatile("s_waitcnt vmcnt(0)" ::: "memory");  // B(k,h1)+A landed
    __syncthreads();

    // ---- half-phase 1: compute kc 2,3 from Bsb[1] ----
    if (k + 1 < K2)
      stageBhalf(Bsb[0], wh + ((size_t)(k + 1) << 14), 0, wave, lane);  // B(k+1,h0)
#pragma unroll
    for (int kc = 2; kc < 4; ++kc) {
      bf16x8 bfr[8];
#pragma unroll
      for (int ni = 0; ni < 8; ++ni)
        bfr[ni] = *(const bf16x8*)&Bsb[1][(ni * 16 + m) * 64 + ((((kc & 1) * 4 + quad) ^ (m & 7)) << 3)];
#pragma unroll
      for (int ni = 0; ni < 8; ++ni) {
        acc[0][ni] = __builtin_amdgcn_mfma_f32_16x16x32_bf16(A[par][0][kc], bfr[ni], acc[0][ni], 0, 0, 0);
        acc[1][ni] = __builtin_amdgcn_mfma_f32_16x16x32_bf16(A[par][1][kc], bfr[ni], acc[1][ni], 0, 0, 0);
      }
    }
    asm volatile("s_waitcnt vmcnt(0)" ::: "memory");
    __syncthreads();
  }

  // ---- epilogue: Bsb (32 KB contiguous) reused, sequenced ----
  const bool full = (n0 + 128 <= NVOX);
  unsigned short* epi = &Bsb[0][0];     // 128x128 bf16 swizzled y-transpose

  // C/D layout: col = lane&15, row = quad*4 + reg
#pragma unroll
  for (int mi = 0; mi < 2; ++mi)
#pragma unroll
    for (int ni = 0; ni < 8; ++ni)
#pragma unroll
      for (int rr = 0; rr < 4; ++rr) {
        int row = wave * 32 + mi * 16 + quad * 4 + rr;
        int col = ni * 16 + m;
        epi[swz(row, col)] = f2b(acc[mi][ni][rr]);
      }

  // BN partials from acc (registers; no LDS yet)
  float psm[8], pq[8];
#pragma unroll
  for (int ni = 0; ni < 8; ++ni) {
    float sm = 0.f, q = 0.f;
#pragma unroll
    for (int mi = 0; mi < 2; ++mi)
#pragma unroll
      for (int rr = 0; rr < 4; ++rr) {
        float v = acc[mi][ni][rr];
        if (!full && n0 + wave * 32 + mi * 16 + quad * 4 + rr >= NVOX) v = 0.f;
        sm += v; q += v * v;
      }
    psm[ni] = sm; pq[ni] = q;
  }
  __syncthreads();

  // coalesced y store (un-swizzle on read)
  for (int i = tid; i < 2048; i += 256) {
    int row = i >> 4;
    int c = i & 15;
    if (n0 + row < NVOX)
      *(bf16x8*)(yb + ((size_t)h * NVOX + n0 + row) * CCH + c * 8) =
          *(const bf16x8*)&epi[row * 128 + ((c ^ (row & 15)) << 3)];
  }
  __syncthreads();   // epi consumed; reuse LDS for pb

  float2* pb = (float2*)&Bsb[0][0];     // [128 cols][17 pad] float2 = 17.4 KB
#pragma unroll
  for (int ni = 0; ni < 8; ++ni)
    pb[(ni * 16 + m) * 17 + wave * 4 + quad] = make_float2(psm[ni], pq[ni]);
  __syncthreads();

  if (tid < 128) {
    float sm = 0.f, q = 0.f;
#pragma unroll
    for (int c = 0; c < 16; ++c) {
      float2 p = pb[tid * 17 + c];
      sm += p.x; q += p.y;
    }
    atomicAdd(&sums[h * CCH + tid], sm);
    atomicAdd(&sums[NH * CCH + h * CCH + tid], q);
  }
}

// ---- BN finalize (per-block, from sums) + BN + ReLU + 1x1 heads ----
__global__ void __launch_bounds__(256) head_fuse(
    const unsigned short* __restrict__ yb, const float* __restrict__ sums,
    const float* __restrict__ gamma, const float* __restrict__ beta,
    const float* __restrict__ w_hm, const float* __restrict__ b_hm,
    const float* __restrict__ w_ce, const float* __restrict__ b_ce,
    const float* __restrict__ w_cz, const float* __restrict__ b_cz,
    const float* __restrict__ w_dm, const float* __restrict__ b_dm,
    const float* __restrict__ w_rt, const float* __restrict__ b_rt,
    float* __restrict__ out)
{
  __shared__ unsigned short t[64 * 128];   // 16 KB, swizzled
  __shared__ float pbuf[4][64][12];        // 12.3 KB
  __shared__ float scl[NH * CCH], shf[NH * CCH];  // 5 KB

  const int tid = threadIdx.x;
  const int v0 = blockIdx.x * 64;          // 625 blocks exactly cover 40000
  const int vx = tid & 63;
  const int qd = tid >> 6;                 // wave-uniform d-quarter

  // inline BN finalize (redundant per block; 640 values)
  for (int i = tid; i < NH * CCH; i += 256) {
    float mean = sums[i] * (1.f / NVOX);
    float var = sums[NH * CCH + i] * (1.f / NVOX) - mean * mean;
    float rstd = rsqrtf(var + 1e-5f);
    float sc = rstd * gamma[i];
    scl[i] = sc;
    shf[i] = beta[i] - mean * sc;
  }

  float part[11];
#pragma unroll
  for (int j = 0; j < 11; ++j) part[j] = 0.f;

#pragma unroll
  for (int h = 0; h < NH; ++h) {
    __syncthreads();  // buffer free (prev head consumed) + scl/shf ready
#pragma unroll
    for (int i = 0; i < 4; ++i) {
      int idx = i * 256 + tid;
      int row = idx >> 4, c = idx & 15;
      *(bf16x8*)&t[row * 128 + ((c ^ (row & 15)) << 3)] =
          *(const bf16x8*)(yb + ((size_t)h * NVOX + v0 + row) * CCH + c * 8);
    }
    __syncthreads();

    const float* sc = scl + h * CCH;
    const float* sh = shf + h * CCH;
    const float* wp; int oc, off;
    switch (h) {
      case 0: wp = w_hm; oc = 3; off = 0; break;
      case 1: wp = w_ce; oc = 2; off = 3; break;
      case 2: wp = w_cz; oc = 1; off = 5; break;
      case 3: wp = w_dm; oc = 3; off = 6; break;
      default: wp = w_rt; oc = 2; off = 9; break;
    }
#pragma unroll
    for (int qq = 0; qq < 4; ++qq) {
      int q8 = qd * 4 + qq;
      bf16x8 pk = *(const bf16x8*)&t[vx * 128 + ((q8 ^ (vx & 15)) << 3)];
#pragma unroll
      for (int e = 0; e < 8; ++e) {
        int d = q8 * 8 + e;
        float z = fmaf(b2f((unsigned short)pk[e]), sc[d], sh[d]);
        z = fmaxf(z, 0.f);
        const float* wr = wp + d * oc;
        part[off] = fmaf(z, wr[0], part[off]);
        if (oc > 1) part[off + 1] = fmaf(z, wr[1], part[off + 1]);
        if (oc > 2) part[off + 2] = fmaf(z, wr[2], part[off + 2]);
      }
    }
  }

#pragma unroll
  for (int j = 0; j < 11; ++j) pbuf[qd][vx][j] = part[j];
  __syncthreads();
  if (tid < 64) {
    float o[11];
#pragma unroll
    for (int j = 0; j < 11; ++j)
      o[j] = pbuf[0][tid][j] + pbuf[1][tid][j] + pbuf[2][tid][j] + pbuf[3][tid][j];
    o[0] += b_hm[0]; o[1] += b_hm[1]; o[2] += b_hm[2];
    o[3] += b_ce[0]; o[4] += b_ce[1];
    o[5] += b_cz[0];
    o[6] += b_dm[0]; o[7] += b_dm[1]; o[8] += b_dm[2];
    o[9] += b_rt[0]; o[10] += b_rt[1];
    float* op = out + (size_t)(v0 + tid) * 11;
#pragma unroll
    for (int j = 0; j < 11; ++j) op[j] = o[j];
  }
}

extern "C" void kernel_launch(void* const* d_in, const int* in_sizes, int n_in,
                              void* d_out, int out_size, void* d_ws, size_t ws_size,
                              hipStream_t stream) {
  const float* feats = (const float*)d_in[0];
  const int*   nbr   = (const int*)d_in[1];
  const float* W1    = (const float*)d_in[2];
  const float* gamma = (const float*)d_in[3];
  const float* beta  = (const float*)d_in[4];
  const float* w_hm = (const float*)d_in[5];  const float* b_hm = (const float*)d_in[6];
  const float* w_ce = (const float*)d_in[7];  const float* b_ce = (const float*)d_in[8];
  const float* w_cz = (const float*)d_in[9];  const float* b_cz = (const float*)d_in[10];
  const float* w_dm = (const float*)d_in[11]; const float* b_dm = (const float*)d_in[12];
  const float* w_rt = (const float*)d_in[13]; const float* b_rt = (const float*)d_in[14];
  float* out = (float*)d_out;

  char* ws = (char*)d_ws;
  unsigned short* w1t = (unsigned short*)ws;                   // 11,796,480 B
  unsigned short* fb  = (unsigned short*)(ws + 11796480);      // 10,240,000 B
  unsigned short* yb  = (unsigned short*)(ws + 22036480);      // 51,200,000 B
  float* sums = (float*)(ws + 73236480);                       // 5,120 B

  prep<<<5181, 256, 0, stream>>>((const float4*)feats, (ushort4*)fb, W1, w1t, sums);
  conv_gemm<<<1600, 256, 0, stream>>>(fb, nbr, w1t, yb, sums);
  head_fuse<<<625, 256, 0, stream>>>(yb, sums, gamma, beta, w_hm, b_hm, w_ce, b_ce,
                                     w_cz, b_cz, w_dm, b_dm, w_rt, b_rt, out);
}

// Round 9
// 241.294 us; speedup vs baseline: 1.0749x; 1.0749x over previous
//
#include <hip/hip_runtime.h>
#include <stdint.h>

#define NVOX 40000
#define CCH  128
#define K2   9
#define NH   5
#define TILES 313   // ceil(40000/128)

typedef __attribute__((ext_vector_type(8))) short bf16x8;
typedef __attribute__((ext_vector_type(4))) float f32x4;

__device__ __forceinline__ unsigned short f2b(float f) {
  union { float f; unsigned int u; } v; v.f = f;
  return (unsigned short)((v.u + 0x7fffu + ((v.u >> 16) & 1u)) >> 16);
}
__device__ __forceinline__ float b2f(unsigned short u) {
  union { unsigned int u; float f; } v; v.u = ((unsigned int)u) << 16;
  return v.f;
}
__device__ __forceinline__ void g2l16(const void* g, void* l) {
  __builtin_amdgcn_global_load_lds(
      (const __attribute__((address_space(1))) unsigned int*)g,
      (__attribute__((address_space(3))) unsigned int*)l, 16, 0, 0);
}
// XOR-swizzled LDS address (shorts) for logical (row, short-col), 128-wide
__device__ __forceinline__ int swz(int row, int col) {
  return row * 128 + ((((col >> 3) ^ (row & 15)) << 3) | (col & 7));
}

// ---- fused prep: feats fp32->bf16 | W1 cvt+transpose (360 blocks) | sums zero ----
__global__ void prep(const float4* __restrict__ feats, ushort4* __restrict__ fb,
                     const float* __restrict__ w1, unsigned short* __restrict__ w1t,
                     float* __restrict__ sums) {
  __shared__ unsigned short t[64 * 34];
  int b = blockIdx.x;
  if (b < 5000) {
    int i = b * 256 + threadIdx.x;
    if (i < NVOX * CCH / 4) {
      float4 v = feats[i];
      ushort4 r;
      r.x = f2b(v.x); r.y = f2b(v.y); r.z = f2b(v.z); r.w = f2b(v.w);
      fb[i] = r;
    }
    return;
  }
  if (b == 5360) {  // zero BN partial sums (ws is poisoned each call)
    for (int i = threadIdx.x; i < 2 * NH * CCH; i += 256) sums[i] = 0.f;
    return;
  }
  int bb = b - 5000;           // 0..359
  int tile = bb >> 3;          // h*9+k, 0..44
  int q = (bb >> 1) & 3;       // c-quarter (32 c each)
  int dh = bb & 1;             // d-half (64 d each)
  const float* src = w1 + (size_t)tile * 16384 + q * 32 * 128 + dh * 64;
  for (int e = threadIdx.x; e < 2048; e += 256) {
    int c = e >> 6, dd = e & 63;
    t[dd * 34 + c] = f2b(src[c * 128 + dd]);
  }
  __syncthreads();
  unsigned short* dst = w1t + (size_t)tile * 16384 + q * 32;
  for (int e = threadIdx.x; e < 2048; e += 256) {
    int d = e >> 5, c = e & 31;
    dst[(dh * 64 + d) * 128 + c] = t[d * 34 + c];
  }
}

// stage one HALF B tile (128 rows x 64 cols = 16 KB) into LDS with 8 waves:
// 2 g2l16 per wave, each covers 8 rows x 64 cols (1 KB). Swizzle: logical
// chunk g of row r stored at slot g ^ (r&7).
__device__ __forceinline__ void stageBhalf8(unsigned short* dst, const unsigned short* wp,
                                            int half, int wave, int lane) {
  int lrow = lane >> 3;   // 0..7
  int lch  = lane & 7;    // chunk slot
#pragma unroll
  for (int i = 0; i < 2; ++i) {
    int blk = wave * 2 + i;          // 0..15, 8 rows each
    g2l16(wp + (blk * 8 + lrow) * 128 + half * 64 + ((lch ^ lrow) << 3),
          &dst[blk * 512]);
  }
}

// ---- gather-GEMM v8: 512 threads / 8 waves, wave owns 16 rows. A fragments
// in registers (double-parity, prefetched during previous tap); B in 16 KB
// half-tiles double-buffered (2x16 KB LDS). Natural VGPR ~116 <= 128 cap ->
// no spill, 2 blocks/CU = 16 waves/CU. ----
__global__ void __launch_bounds__(512, 4) conv_gemm(
    const unsigned short* __restrict__ fb,   // feats bf16 [N][128]
    const int* __restrict__ nbr,             // [N][9]
    const unsigned short* __restrict__ w1t,  // [H][9][d=128][c=128] bf16
    unsigned short* __restrict__ yb,         // [H][N][128] bf16
    float* __restrict__ sums)                // [2][H][128]
{
  __shared__ __align__(16) unsigned short Bsb[2][64 * 128];   // 2 x 16 KB
  __shared__ int idxs[128 * K2];                              // 4.6 KB

  const int bid = blockIdx.x;
  const int s = bid / 40;
  const int r = bid % 40;
  const int h = r >> 3;        // 0..4
  const int x = r & 7;         // xcd lane
  const int tile = s * 8 + x;
  if (tile >= TILES) return;
  const int n0 = tile * 128;

  const int tid = threadIdx.x;
  const int wave = tid >> 6;   // 0..7
  const int lane = tid & 63;
  const int m = lane & 15;     // position within 16
  const int quad = lane >> 4;  // 0..3

  const unsigned short* wh = w1t + ((size_t)h * K2 << 14);

  // phase (k=0, half=0) stage first (no dependencies)
  stageBhalf8(Bsb[0], wh, 0, wave, lane);

  for (int i = tid; i < 128 * K2; i += 512) {
    int rr = i / K2;
    int gn = n0 + rr; if (gn > NVOX - 1) gn = NVOX - 1;
    idxs[i] = nbr[gn * K2 + (i - rr * K2)];
  }
  __syncthreads();   // idxs visible

  // A parity registers: [par][kc], wave-private rows (row = wave*16 + m)
  bf16x8 A[2][4];
  {
    int i0 = idxs[(wave * 16 + m) * K2 + 0];
    const unsigned short* p0 = fb + (size_t)i0 * CCH + quad * 8;
#pragma unroll
    for (int kc = 0; kc < 4; ++kc)
      A[0][kc] = *(const bf16x8*)(p0 + kc * 32);
  }
  asm volatile("s_waitcnt vmcnt(0)" ::: "memory");
  __syncthreads();   // B(0,h0) + A(0) ready

  f32x4 acc[8] = {};

#pragma unroll
  for (int k = 0; k < K2; ++k) {
    const int par = k & 1;

    // ---- half-phase 0: stage B(k,h1); prefetch A(k+1); compute kc 0,1 ----
    stageBhalf8(Bsb[1], wh + ((size_t)k << 14), 1, wave, lane);
    if (k + 1 < K2) {
      int i0 = idxs[(wave * 16 + m) * K2 + k + 1];
      const unsigned short* p0 = fb + (size_t)i0 * CCH + quad * 8;
#pragma unroll
      for (int kc = 0; kc < 4; ++kc)
        A[par ^ 1][kc] = *(const bf16x8*)(p0 + kc * 32);
    }
#pragma unroll
    for (int kc = 0; kc < 2; ++kc) {
      bf16x8 bfr[8];
#pragma unroll
      for (int ni = 0; ni < 8; ++ni)
        bfr[ni] = *(const bf16x8*)&Bsb[0][(ni * 16 + m) * 64 + ((((kc & 1) * 4 + quad) ^ (m & 7)) << 3)];
#pragma unroll
      for (int ni = 0; ni < 8; ++ni)
        acc[ni] = __builtin_amdgcn_mfma_f32_16x16x32_bf16(A[par][kc], bfr[ni], acc[ni], 0, 0, 0);
    }
    asm volatile("s_waitcnt vmcnt(0)" ::: "memory");
    __syncthreads();

    // ---- half-phase 1: stage B(k+1,h0); compute kc 2,3 ----
    if (k + 1 < K2)
      stageBhalf8(Bsb[0], wh + ((size_t)(k + 1) << 14), 0, wave, lane);
#pragma unroll
    for (int kc = 2; kc < 4; ++kc) {
      bf16x8 bfr[8];
#pragma unroll
      for (int ni = 0; ni < 8; ++ni)
        bfr[ni] = *(const bf16x8*)&Bsb[1][(ni * 16 + m) * 64 + ((((kc & 1) * 4 + quad) ^ (m & 7)) << 3)];
#pragma unroll
      for (int ni = 0; ni < 8; ++ni)
        acc[ni] = __builtin_amdgcn_mfma_f32_16x16x32_bf16(A[par][kc], bfr[ni], acc[ni], 0, 0, 0);
    }
    asm volatile("s_waitcnt vmcnt(0)" ::: "memory");
    __syncthreads();
  }

  // ---- epilogue (last loop iteration ended with a barrier) ----
  const bool full = (n0 + 128 <= NVOX);
  unsigned short* epi = &Bsb[0][0];     // 128x128 bf16 swizzled y-transpose (32 KB)

  // C/D layout: col = lane&15, row = quad*4 + reg; wave rows disjoint
#pragma unroll
  for (int ni = 0; ni < 8; ++ni)
#pragma unroll
    for (int rr = 0; rr < 4; ++rr) {
      int row = wave * 16 + quad * 4 + rr;
      int col = ni * 16 + m;
      epi[swz(row, col)] = f2b(acc[ni][rr]);
    }

  // BN partials from acc; quad-reduce via shfl (no LDS)
  float psm[8], pq[8];
#pragma unroll
  for (int ni = 0; ni < 8; ++ni) {
    float sm = 0.f, q = 0.f;
#pragma unroll
    for (int rr = 0; rr < 4; ++rr) {
      float v = acc[ni][rr];
      if (!full && n0 + wave * 16 + quad * 4 + rr >= NVOX) v = 0.f;
      sm += v; q += v * v;
    }
    sm += __shfl_xor(sm, 16); q += __shfl_xor(q, 16);
    sm += __shfl_xor(sm, 32); q += __shfl_xor(q, 32);
    psm[ni] = sm; pq[ni] = q;
  }
  __syncthreads();   // epi writes complete

  // coalesced y store (un-swizzle on read)
  for (int i = tid; i < 2048; i += 512) {
    int row = i >> 4;
    int c = i & 15;
    if (n0 + row < NVOX)
      *(bf16x8*)(yb + ((size_t)h * NVOX + n0 + row) * CCH + c * 8) =
          *(const bf16x8*)&epi[row * 128 + ((c ^ (row & 15)) << 3)];
  }
  __syncthreads();   // epi consumed; reuse LDS for pb

  float2* pb = (float2*)&Bsb[0][0];     // [128 cols][9 pad] float2 = 9.2 KB
  if (quad == 0)
#pragma unroll
    for (int ni = 0; ni < 8; ++ni)
      pb[(ni * 16 + m) * 9 + wave] = make_float2(psm[ni], pq[ni]);
  __syncthreads();

  if (tid < 128) {
    float sm = 0.f, q = 0.f;
#pragma unroll
    for (int c = 0; c < 8; ++c) {
      float2 p = pb[tid * 9 + c];
      sm += p.x; q += p.y;
    }
    atomicAdd(&sums[h * CCH + tid], sm);
    atomicAdd(&sums[NH * CCH + h * CCH + tid], q);
  }
}

// ---- BN finalize (per-block, from sums) + BN + ReLU + 1x1 heads ----
__global__ void __launch_bounds__(256) head_fuse(
    const unsigned short* __restrict__ yb, const float* __restrict__ sums,
    const float* __restrict__ gamma, const float* __restrict__ beta,
    const float* __restrict__ w_hm, const float* __restrict__ b_hm,
    const float* __restrict__ w_ce, const float* __restrict__ b_ce,
    const float* __restrict__ w_cz, const float* __restrict__ b_cz,
    const float* __restrict__ w_dm, const float* __restrict__ b_dm,
    const float* __restrict__ w_rt, const float* __restrict__ b_rt,
    float* __restrict__ out)
{
  __shared__ unsigned short t[64 * 128];   // 16 KB, swizzled
  __shared__ float pbuf[4][64][12];        // 12.3 KB
  __shared__ float scl[NH * CCH], shf[NH * CCH];  // 5 KB

  const int tid = threadIdx.x;
  const int v0 = blockIdx.x * 64;          // 625 blocks exactly cover 40000
  const int vx = tid & 63;
  const int qd = tid >> 6;                 // wave-uniform d-quarter

  // inline BN finalize (redundant per block; 640 values)
  for (int i = tid; i < NH * CCH; i += 256) {
    float mean = sums[i] * (1.f / NVOX);
    float var = sums[NH * CCH + i] * (1.f / NVOX) - mean * mean;
    float rstd = rsqrtf(var + 1e-5f);
    float sc = rstd * gamma[i];
    scl[i] = sc;
    shf[i] = beta[i] - mean * sc;
  }

  float part[11];
#pragma unroll
  for (int j = 0; j < 11; ++j) part[j] = 0.f;

#pragma unroll
  for (int h = 0; h < NH; ++h) {
    __syncthreads();  // buffer free (prev head consumed) + scl/shf ready
#pragma unroll
    for (int i = 0; i < 4; ++i) {
      int idx = i * 256 + tid;
      int row = idx >> 4, c = idx & 15;
      *(bf16x8*)&t[row * 128 + ((c ^ (row & 15)) << 3)] =
          *(const bf16x8*)(yb + ((size_t)h * NVOX + v0 + row) * CCH + c * 8);
    }
    __syncthreads();

    const float* sc = scl + h * CCH;
    const float* sh = shf + h * CCH;
    const float* wp; int oc, off;
    switch (h) {
      case 0: wp = w_hm; oc = 3; off = 0; break;
      case 1: wp = w_ce; oc = 2; off = 3; break;
      case 2: wp = w_cz; oc = 1; off = 5; break;
      case 3: wp = w_dm; oc = 3; off = 6; break;
      default: wp = w_rt; oc = 2; off = 9; break;
    }
#pragma unroll
    for (int qq = 0; qq < 4; ++qq) {
      int q8 = qd * 4 + qq;
      bf16x8 pk = *(const bf16x8*)&t[vx * 128 + ((q8 ^ (vx & 15)) << 3)];
#pragma unroll
      for (int e = 0; e < 8; ++e) {
        int d = q8 * 8 + e;
        float z = fmaf(b2f((unsigned short)pk[e]), sc[d], sh[d]);
        z = fmaxf(z, 0.f);
        const float* wr = wp + d * oc;
        part[off] = fmaf(z, wr[0], part[off]);
        if (oc > 1) part[off + 1] = fmaf(z, wr[1], part[off + 1]);
        if (oc > 2) part[off + 2] = fmaf(z, wr[2], part[off + 2]);
      }
    }
  }

#pragma unroll
  for (int j = 0; j < 11; ++j) pbuf[qd][vx][j] = part[j];
  __syncthreads();
  if (tid < 64) {
    float o[11];
#pragma unroll
    for (int j = 0; j < 11; ++j)
      o[j] = pbuf[0][tid][j] + pbuf[1][tid][j] + pbuf[2][tid][j] + pbuf[3][tid][j];
    o[0] += b_hm[0]; o[1] += b_hm[1]; o[2] += b_hm[2];
    o[3] += b_ce[0]; o[4] += b_ce[1];
    o[5] += b_cz[0];
    o[6] += b_dm[0]; o[7] += b_dm[1]; o[8] += b_dm[2];
    o[9] += b_rt[0]; o[10] += b_rt[1];
    float* op = out + (size_t)(v0 + tid) * 11;
#pragma unroll
    for (int j = 0; j < 11; ++j) op[j] = o[j];
  }
}

extern "C" void kernel_launch(void* const* d_in, const int* in_sizes, int n_in,
                              void* d_out, int out_size, void* d_ws, size_t ws_size,
                              hipStream_t stream) {
  const float* feats = (const float*)d_in[0];
  const int*   nbr   = (const int*)d_in[1];
  const float* W1    = (const float*)d_in[2];
  const float* gamma = (const float*)d_in[3];
  const float* beta  = (const float*)d_in[4];
  const float* w_hm = (const float*)d_in[5];  const float* b_hm = (const float*)d_in[6];
  const float* w_ce = (const float*)d_in[7];  const float* b_ce = (const float*)d_in[8];
  const float* w_cz = (const float*)d_in[9];  const float* b_cz = (const float*)d_in[10];
  const float* w_dm = (const float*)d_in[11]; const float* b_dm = (const float*)d_in[12];
  const float* w_rt = (const float*)d_in[13]; const float* b_rt = (const float*)d_in[14];
  float* out = (float*)d_out;

  char* ws = (char*)d_ws;
  unsigned short* w1t = (unsigned short*)ws;                   // 11,796,480 B
  unsigned short* fb  = (unsigned short*)(ws + 11796480);      // 10,240,000 B
  unsigned short* yb  = (unsigned short*)(ws + 22036480);      // 51,200,000 B
  float* sums = (float*)(ws + 73236480);                       // 5,120 B

  prep<<<5361, 256, 0, stream>>>((const float4*)feats, (ushort4*)fb, W1, w1t, sums);
  conv_gemm<<<1600, 512, 0, stream>>>(fb, nbr, w1t, yb, sums);
  head_fuse<<<625, 256, 0, stream>>>(yb, sums, gamma, beta, w_hm, b_hm, w_ce, b_ce,
                                     w_cz, b_cz, w_dm, b_dm, w_rt, b_rt, out);
}